// Round 5
// baseline (304.786 us; speedup 1.0000x reference)
//
#include <hip/hip_runtime.h>
#include <stdint.h>

#define NTOK 2048
#define DIM  1024
#define HID  2048
#define NEXP 8
#define CAP  4224   // 4096 assignments + 256 tile-overflow pad (BM=256)
#define RB   256    // router blocks

typedef __attribute__((ext_vector_type(8))) short short8;
typedef __attribute__((ext_vector_type(4))) float floatx4;
typedef __attribute__((ext_vector_type(4))) unsigned short ushortx4;
typedef __attribute__((ext_vector_type(4))) uint32_t uintx4;

static __device__ __forceinline__ unsigned short f2bf(float f) {
  uint32_t u = __builtin_bit_cast(uint32_t, f);
  u += 0x7fffu + ((u >> 16) & 1u);   // round-to-nearest-even
  return (unsigned short)(u >> 16);
}

// ---------------- router (fp32 exact, no atomics) ----------------
__global__ void __launch_bounds__(256) router_kernel(const float* __restrict__ x,
                                                     const float* __restrict__ Wr,
                                                     int* __restrict__ experts,
                                                     float* __restrict__ wts) {
  const int wave = threadIdx.x >> 6;
  const int lane = threadIdx.x & 63;

#pragma unroll
  for (int j = 0; j < 2; j++) {
    int t = blockIdx.x * 8 + wave * 2 + j;
    const float* xr = x + (size_t)t * DIM;
    float acc[NEXP];
#pragma unroll
    for (int e = 0; e < NEXP; e++) acc[e] = 0.f;
#pragma unroll
    for (int i = 0; i < 4; i++) {
      floatx4 v = ((const floatx4*)xr)[i * 64 + lane];
      int idx = (i * 64 + lane) * 4;
#pragma unroll
      for (int e = 0; e < NEXP; e++) {
        floatx4 w = *(const floatx4*)&Wr[e * DIM + idx];
        acc[e] += v.x * w.x + v.y * w.y + v.z * w.z + v.w * w.w;
      }
    }
#pragma unroll
    for (int e = 0; e < NEXP; e++) {
#pragma unroll
      for (int off = 32; off > 0; off >>= 1) acc[e] += __shfl_down(acc[e], off);
    }
    if (lane == 0) {
      float mx = acc[0];
      for (int e = 1; e < NEXP; e++) mx = fmaxf(mx, acc[e]);
      float p[NEXP], s = 0.f;
      for (int e = 0; e < NEXP; e++) { p[e] = expf(acc[e] - mx); s += p[e]; }
      float inv = 1.f / s;
      for (int e = 0; e < NEXP; e++) p[e] *= inv;
      int i0 = 0; float p0 = p[0];
      for (int e = 1; e < NEXP; e++) if (p[e] > p0) { p0 = p[e]; i0 = e; }   // ties: lowest idx
      int i1 = -1; float p1 = -1.f;
      for (int e = 0; e < NEXP; e++) if (e != i0 && p[e] > p1) { p1 = p[e]; i1 = e; }
      float rn = 1.f / (p0 + p1 + 1e-8f);
      experts[2 * t] = i0; experts[2 * t + 1] = i1;
      wts[2 * t] = p0 * rn; wts[2 * t + 1] = p1 * rn;
    }
  }
}

// ------- scanpos: 8 waves, one expert each (was 1 wave x 8 experts serially).
// Emits counts, bases, pos[a] (scatter target per assignment) and the inverse
// map afor[p] (assignment for position) used by gemm2's fused combine.
__global__ void __launch_bounds__(512) scanpos_kernel(const int* __restrict__ experts,
                                                      int* __restrict__ ctrl,
                                                      int* __restrict__ pos,
                                                      int* __restrict__ afor) {
  const int wv = threadIdx.x >> 6;    // expert owned by this wave
  const int lane = threadIdx.x & 63;
  __shared__ int scnt[NEXP];
  int cnt = 0;
  for (int c = 0; c < 2 * NTOK / 64; c++) {
    int v = experts[c * 64 + lane];
    cnt += __popcll(__ballot(v == wv));
  }
  if (lane == 0) scnt[wv] = cnt;
  __syncthreads();
  int basev = 0;
#pragma unroll
  for (int e = 0; e < NEXP; e++) { int ce = scnt[e]; if (e < wv) basev += ce; }
  if (lane == 0) { ctrl[wv] = cnt; ctrl[8 + wv] = basev; }
  unsigned long long below = (1ull << lane) - 1ull;
  int cur = basev;
  for (int c = 0; c < 2 * NTOK / 64; c++) {
    int a = c * 64 + lane;
    int v = experts[a];
    unsigned long long m = __ballot(v == wv);
    if (v == wv) {
      int p = cur + __popcll(m & below);
      pos[a] = p;
      afor[p] = a;
    }
    cur += __popcll(m);
  }
}

// ---------------- gather: compact token rows into Xe (bf16) ------------------
__global__ void __launch_bounds__(256) gather_kernel(const float* __restrict__ x,
                                                     const int* __restrict__ pos,
                                                     unsigned short* __restrict__ Xe) {
  int t = blockIdx.x;
  int p0 = pos[2 * t], p1 = pos[2 * t + 1];
  int i = threadIdx.x;
  floatx4 v = ((const floatx4*)(x + (size_t)t * DIM))[i];
  ushortx4 b;
  b.x = f2bf(v.x); b.y = f2bf(v.y); b.z = f2bf(v.z); b.w = f2bf(v.w);
  *(ushortx4*)(Xe + (size_t)p0 * DIM + 4 * i) = b;
  *(ushortx4*)(Xe + (size_t)p1 * DIM + 4 * i) = b;
}

// ------------- BM=256 x BN=128 bf16 GEMM, fused fp32->bf16 B -----------------
// TRAFFIC-optimal shape (r4 post-mortem: 128x128 was BW-bound at 4.7 TB/s with
// 393 MB moved): BM=2*BN since fp32 B costs 2x bf16 A per row. 8 waves (512
// thr), each wave the proven 64x64 / 4x4-frag block. 2-phase dbuf kept.
// KSPLIT: gemm2 (K=2048) splits K across 2 blocks to keep all 256 CUs active;
// partials combined via f32 atomicAdd (commutative; out pre-zeroed).
// EPI=0: relu(C)^2 -> bf16 store to He.
// EPI=1: FUSED COMBINE — scale by wts[afor[p]] and atomicAdd into out.
template <int K, int N, int KSPLIT, int EPI>
__global__ void __launch_bounds__(512) gemm_kernel(const unsigned short* __restrict__ A,
                                                   const float* __restrict__ B,
                                                   unsigned short* __restrict__ Cbf,
                                                   float* __restrict__ outp,
                                                   const int* __restrict__ ctrl,
                                                   const int* __restrict__ afor,
                                                   const float* __restrict__ wts) {
  const int e = blockIdx.z;
  const int cnt = ctrl[e];
  const int my = blockIdx.y / KSPLIT;
  const int kh = blockIdx.y % KSPLIT;
  const int m0 = my * 256;
  if (m0 >= cnt) return;
  const int base = ctrl[8 + e];
  const int n0 = blockIdx.x * 128;
  constexpr int KC = K / KSPLIT;       // K-chunk this block reduces (1024)
  const int kbeg = kh * KC;

  __shared__ __align__(16) unsigned short ldsA[2][256 * 64];  // 2 x 32 KB
  __shared__ __align__(16) unsigned short ldsB[2][128 * 64];  // 2 x 16 KB

  const int tid = threadIdx.x;
  const int lane = tid & 63;
  const int wave = tid >> 6;           // 0..7
  const int wm = wave >> 1;            // 0..3 (m-dir)
  const int wn = wave & 1;             // 0..1 (n-dir)

  const unsigned short* Ae = A + (size_t)(base + m0) * K;
  const float* Be = B + ((size_t)e * N + n0) * (size_t)K;

  const int rsub = lane >> 3;          // A: row within 8-row chunk
  const int sg = lane & 7;             // A: 16B granule slot
  const int brow = lane >> 3;          // B: row within 8-row unit
  const int bg = lane & 7;             // B: dest bf16 granule (16B)

  floatx4 acc[4][4];
  floatx4 zero = {0.f, 0.f, 0.f, 0.f};
#pragma unroll
  for (int i = 0; i < 4; i++)
#pragma unroll
    for (int j = 0; j < 4; j++) acc[i][j] = zero;

  floatx4 rb0[2], rb1[2];   // B staging regs (2 units), live across COMPUTE

  // A: 32 gll instrs (4/wave), 8 rows each, XOR-swizzled source, linear dest.
#define STAGE_A(k0, buf)                                                                        \
  _Pragma("unroll")                                                                             \
  for (int j = 0; j < 4; j++) {                                                                 \
    int c = wave * 4 + j;                                                                       \
    int rc = c * 8 + rsub;                                                                      \
    int g = sg ^ (rc & 7);                                                                      \
    const unsigned short* ga = Ae + (size_t)rc * K + (k0) + g * 8;                              \
    __builtin_amdgcn_global_load_lds((const __attribute__((address_space(1))) unsigned int*)ga, \
                                     (__attribute__((address_space(3))) unsigned int*)&ldsA[buf][c * 512], \
                                     16, 0, 0);                                                 \
  }

  // B: per wave 2 units x 8 rows; each thread owns dest granule bg of row ru:
  // loads the swizzled global granule (8 fp32 = 2 float4), cvt, 1 ds_write_b128.
#define LOAD_B(k0)                                                                              \
  _Pragma("unroll")                                                                             \
  for (int u = 0; u < 2; u++) {                                                                 \
    int ru = wave * 16 + u * 8 + brow;                                                          \
    int gs = bg ^ (ru & 7);                                                                     \
    const float* gb = Be + (size_t)ru * K + (k0) + gs * 8;                                      \
    rb0[u] = ((const floatx4*)gb)[0];                                                           \
    rb1[u] = ((const floatx4*)gb)[1];                                                           \
  }

#define WRITE_B(buf)                                                                            \
  _Pragma("unroll")                                                                             \
  for (int u = 0; u < 2; u++) {                                                                 \
    int ru = wave * 16 + u * 8 + brow;                                                          \
    uintx4 uu;                                                                                  \
    asm("v_cvt_pk_bf16_f32 %0, %1, %2" : "=v"(uu.x) : "v"(rb0[u].x), "v"(rb0[u].y));            \
    asm("v_cvt_pk_bf16_f32 %0, %1, %2" : "=v"(uu.y) : "v"(rb0[u].z), "v"(rb0[u].w));            \
    asm("v_cvt_pk_bf16_f32 %0, %1, %2" : "=v"(uu.z) : "v"(rb1[u].x), "v"(rb1[u].y));            \
    asm("v_cvt_pk_bf16_f32 %0, %1, %2" : "=v"(uu.w) : "v"(rb1[u].z), "v"(rb1[u].w));            \
    *(short8*)&ldsB[buf][ru * 64 + bg * 8] = __builtin_bit_cast(short8, uu);                    \
  }

#define COMPUTE(buf)                                                                            \
  _Pragma("unroll")                                                                             \
  for (int kk = 0; kk < 2; kk++) {                                                              \
    int gk = kk * 4 + (lane >> 4);                                                              \
    short8 af[4], bfr[4];                                                                       \
    _Pragma("unroll")                                                                           \
    for (int mi = 0; mi < 4; mi++) {                                                            \
      int row = wm * 64 + mi * 16 + (lane & 15);                                                \
      af[mi] = *(const short8*)&ldsA[buf][row * 64 + (gk ^ (row & 7)) * 8];                     \
    }                                                                                           \
    _Pragma("unroll")                                                                           \
    for (int ni = 0; ni < 4; ni++) {                                                            \
      int row = wn * 64 + ni * 16 + (lane & 15);                                                \
      bfr[ni] = *(const short8*)&ldsB[buf][row * 64 + (gk ^ (row & 7)) * 8];                    \
    }                                                                                           \
    _Pragma("unroll")                                                                           \
    for (int mi = 0; mi < 4; mi++)                                                              \
      _Pragma("unroll")                                                                         \
      for (int ni = 0; ni < 4; ni++)                                                            \
        acc[mi][ni] = __builtin_amdgcn_mfma_f32_16x16x32_bf16(af[mi], bfr[ni], acc[mi][ni], 0, 0, 0); \
  }

  constexpr int NT = KC / 64;

  // prologue: tile 0 into buf 0
  LOAD_B(kbeg)
  STAGE_A(kbeg, 0)
  WRITE_B(0)                             // waits only on B loads (data dep)
  __builtin_amdgcn_s_waitcnt(0x0f70);    // vmcnt(0): A gll drained
  __syncthreads();

  for (int t = 0; t < NT; ++t) {
    int cur = t & 1, nxt = cur ^ 1;
    if (t + 1 < NT) {
      LOAD_B(kbeg + (t + 1) * 64)
      STAGE_A(kbeg + (t + 1) * 64, nxt)
    }
    COMPUTE(cur)
    if (t + 1 < NT) {
      WRITE_B(nxt)
      __builtin_amdgcn_s_waitcnt(0x0f70);
      __syncthreads();
    }
  }

  // epilogue: D row=(lane>>4)*4+reg, col=lane&15; mask past cnt.
  const int lm = lane >> 4;
  const int ln = lane & 15;
#pragma unroll
  for (int mi = 0; mi < 4; mi++) {
#pragma unroll
    for (int r = 0; r < 4; r++) {
      int row = m0 + wm * 64 + mi * 16 + lm * 4 + r;   // local row in expert segment
      if (row < cnt) {
        if (EPI == 0) {
#pragma unroll
          for (int ni = 0; ni < 4; ni++) {
            int col = n0 + wn * 64 + ni * 16 + ln;
            float v = fmaxf(acc[mi][ni][r], 0.f);
            v = v * v;
            Cbf[(size_t)(base + row) * N + col] = f2bf(v);
          }
        } else {
          int a = afor[base + row];
          float w = wts[a];
          size_t tok = (size_t)(a >> 1);
#pragma unroll
          for (int ni = 0; ni < 4; ni++) {
            int col = n0 + wn * 64 + ni * 16 + ln;
            atomicAdd(&outp[tok * DIM + col], w * acc[mi][ni][r]);
          }
        }
      }
    }
  }
#undef STAGE_A
#undef LOAD_B
#undef WRITE_B
#undef COMPUTE
}

extern "C" void kernel_launch(void* const* d_in, const int* in_sizes, int n_in,
                              void* d_out, int out_size, void* d_ws, size_t ws_size,
                              hipStream_t stream) {
  const float* x   = (const float*)d_in[0];
  const float* Wr  = (const float*)d_in[1];
  const float* Wfc = (const float*)d_in[2];
  const float* Wpr = (const float*)d_in[3];
  float* out = (float*)d_out;
  char* ws = (char*)d_ws;

  int*   ctrl    = (int*)ws;                   // counts[8] bases[8]
  int*   experts = (int*)(ws + 1024);          // int2 per token (16 KB)
  int*   pos     = (int*)(ws + 1024 + 16384);  // int2 per token (16 KB)
  float* wts     = (float*)(ws + 33792);       // float2 per token (16 KB)
  int*   afor    = (int*)(ws + 50176);         // assignment-for-position (CAP ints)
  unsigned short* Xe = (unsigned short*)(ws + 131072);  // [CAP x DIM] bf16
  unsigned short* He = Xe + (size_t)CAP * DIM;          // [CAP x HID] bf16

  hipMemsetAsync(out, 0, out_size, stream);    // fused-combine accumulates into out

  router_kernel<<<RB, 256, 0, stream>>>(x, Wr, experts, wts);
  scanpos_kernel<<<1, 512, 0, stream>>>(experts, ctrl, pos, afor);
  gather_kernel<<<NTOK, 256, 0, stream>>>(x, pos, Xe);

  gemm_kernel<DIM, HID, 1, 0><<<dim3(HID / 128, 16, NEXP), 512, 0, stream>>>(Xe, Wfc, He, nullptr, ctrl, nullptr, nullptr);
  gemm_kernel<HID, DIM, 2, 1><<<dim3(DIM / 128, 32, NEXP), 512, 0, stream>>>(He, Wpr, nullptr, out, ctrl, afor, wts);
}